// Round 2
// baseline (38.344 us; speedup 1.0000x reference)
//
#include <hip/hip_runtime.h>
#include <math.h>

#define KK 27
#define MM 4
#define OUTC 32
#define GG 64
#define DILF 0.05f
#define MAXDF 1.0f
#define MU 4e-3f   // ambiguity margin in grid-units (u-space); FP drift bound ~1e-4

// Bit-exact (numpy op order, no FMA contraction, IEEE div) in-bounds test.
static __device__ inline bool exact_inb(float lx, float ly, float lz,
                                        float ox, float oy, float oz,
                                        float tx, float ty, float tz,
                                        float qx, float qy, float qz, float qw,
                                        float sc, float gcs) {
#pragma clang fp contract(off)
    float px = lx + ox, py = ly + oy, pz = lz + oz;
    float vx = px - tx, vy = py - ty, vz = pz - tz;
    float ux = -qx, uy = -qy, uz = -qz;
    float cx = uy * vz - uz * vy;
    float cy = uz * vx - ux * vz;
    float cz = ux * vy - uy * vx;
    float twx = cx + qw * vx;
    float twy = cy + qw * vy;
    float twz = cz + qw * vz;
    float rx = vx + 2.0f * (uy * twz - uz * twy);
    float ry = vy + 2.0f * (uz * twx - ux * twz);
    float rz = vz + 2.0f * (ux * twy - uy * twx);
    rx = rx / sc; ry = ry / sc; rz = rz / sc;
    return (rx >= 0.0f) & (rx <= gcs) & (ry >= 0.0f) & (ry <= gcs) &
           (rz >= 0.0f) & (rz <= gcs);
}

// ---------------- Kernel P: per-point rotated bases (u-space) ----------------
__global__ __launch_bounds__(256) void prep_kernel(
    const float* __restrict__ locs, const int* __restrict__ idxs,
    const float* __restrict__ poses, const float* __restrict__ scales,
    const float* __restrict__ cells, float* __restrict__ bu, int N) {
    __shared__ float s_t[MM][3];
    __shared__ float s_q[MM][4];
    __shared__ float s_invscs[MM];
    const int b = blockIdx.y;
    const int tid = threadIdx.x;
    if (tid < MM) {
        int m = tid;
        const float* pp = poses + (b * MM + m) * 7;
        s_t[m][0] = pp[0]; s_t[m][1] = pp[1]; s_t[m][2] = pp[2];
        s_q[m][0] = pp[3]; s_q[m][1] = pp[4]; s_q[m][2] = pp[5]; s_q[m][3] = pp[6];
        float sc = scales[b * MM + m];
        float cs = cells[idxs[b * MM + m]];
        s_invscs[m] = 1.0f / (sc * cs);
    }
    __syncthreads();
    int n = blockIdx.x * 256 + tid;
    if (n >= N) return;
    const float* lp = locs + (size_t)(b * N + n) * 3;
    float lx = lp[0], ly = lp[1], lz = lp[2];
    float v12[12];
#pragma unroll
    for (int m = 0; m < MM; ++m) {
        float vx = lx - s_t[m][0], vy = ly - s_t[m][1], vz = lz - s_t[m][2];
        float qx = s_q[m][0], qy = s_q[m][1], qz = s_q[m][2], qw = s_q[m][3];
        float ux = -qx, uy = -qy, uz = -qz;
        float cx = uy * vz - uz * vy + qw * vx;
        float cy = uz * vx - ux * vz + qw * vy;
        float cz = ux * vy - uy * vx + qw * vz;
        float rx = vx + 2.0f * (uy * cz - uz * cy);
        float ry = vy + 2.0f * (uz * cx - ux * cz);
        float rz = vz + 2.0f * (ux * cy - uy * cx);
        float f = s_invscs[m];
        v12[3 * m + 0] = rx * f;
        v12[3 * m + 1] = ry * f;
        v12[3 * m + 2] = rz * f;
    }
    float4* op = (float4*)(bu + (size_t)(b * N + n) * 12);
    op[0] = make_float4(v12[0], v12[1], v12[2], v12[3]);
    op[1] = make_float4(v12[4], v12[5], v12[6], v12[7]);
    op[2] = make_float4(v12[8], v12[9], v12[10], v12[11]);
}

// ------------- Kernel A: one thread per (point, k) -> d[b][n][k] -------------
__global__ __launch_bounds__(256) void sample_kernel(
    const float* __restrict__ locs, const int* __restrict__ idxs,
    const float* __restrict__ poses, const float* __restrict__ scales,
    const float* __restrict__ sdf, const float* __restrict__ cells,
    const float* __restrict__ bu, float* __restrict__ dd, int N) {
    __shared__ float4 s_ro[MM][KK];
    __shared__ float4 s_off[KK];
    __shared__ float  s_t[MM][3];
    __shared__ float  s_q[MM][4];
    __shared__ float  s_sc[MM];
    __shared__ float  s_gcs[MM];
    __shared__ float  s_invscs[MM];
    __shared__ int    s_goff[MM];

    const int b = blockIdx.y;
    const int tid = threadIdx.x;

    if (tid < KK) {
        int kx = tid / 9, ky = (tid / 3) % 3, kz = tid % 3;
        s_off[tid] = make_float4((float)(kx - 1) * DILF, (float)(ky - 1) * DILF,
                                 (float)(kz - 1) * DILF, 0.0f);
    }
    if (tid >= 128 && tid < 128 + MM) {
        int m = tid - 128;
        const float* pp = poses + (b * MM + m) * 7;
        float sc = scales[b * MM + m];
        int gi = idxs[b * MM + m];
        float cs = cells[gi];
        s_t[m][0] = pp[0]; s_t[m][1] = pp[1]; s_t[m][2] = pp[2];
        s_q[m][0] = pp[3]; s_q[m][1] = pp[4]; s_q[m][2] = pp[5]; s_q[m][3] = pp[6];
        s_sc[m] = sc;
        s_gcs[m] = (float)GG * cs;
        s_invscs[m] = 1.0f / (sc * cs);
        s_goff[m] = gi * GG * GG * GG;
    }
    __syncthreads();

    if (tid < MM * KK) {
        int m = tid / KK, k = tid - m * KK;
        float4 off = s_off[k];
        float qx = s_q[m][0], qy = s_q[m][1], qz = s_q[m][2], qw = s_q[m][3];
        float ux = -qx, uy = -qy, uz = -qz;
        float vx = off.x, vy = off.y, vz = off.z;
        float cx = uy * vz - uz * vy + qw * vx;
        float cy = uz * vx - ux * vz + qw * vy;
        float cz = ux * vy - uy * vx + qw * vz;
        float rx = vx + 2.0f * (uy * cz - uz * cy);
        float ry = vy + 2.0f * (uz * cx - ux * cz);
        float rz = vz + 2.0f * (ux * cy - uy * cx);
        float f = s_invscs[m];
        s_ro[m][k] = make_float4(rx * f, ry * f, rz * f, 0.0f);
    }
    __syncthreads();

    int i = blockIdx.x * 256 + tid;
    if (i >= N * KK) return;
    int n = i / KK;           // compiler magic-mul division
    int k = i - n * KK;

    const float4* bp = (const float4*)(bu + (size_t)(b * N + n) * 12);
    float4 r0 = bp[0], r1 = bp[1], r2 = bp[2];
    float bux[MM] = {r0.x, r0.w, r1.z, r2.y};
    float buy[MM] = {r0.y, r1.x, r1.w, r2.z};
    float buz[MM] = {r0.z, r1.y, r2.x, r2.w};

    float dk = MAXDF;
#pragma unroll
    for (int m = 0; m < MM; ++m) {
        float4 ro = s_ro[m][k];
        float ux = bux[m] + ro.x;
        float uy = buy[m] + ro.y;
        float uz = buz[m] + ro.z;
        float mn = fminf(fminf(ux, uy), uz);
        float mx = fmaxf(fmaxf(ux, uy), uz);
        bool inb = (mn >= 0.0f) & (mx <= 64.0f);
        float a0 = fminf(fminf(fabsf(ux), fabsf(uy)), fabsf(uz));
        float a1 = fminf(fminf(fabsf(ux - 64.0f), fabsf(uy - 64.0f)),
                         fabsf(uz - 64.0f));
        if (fminf(a0, a1) < MU) {
            const float* lp = locs + (size_t)(b * N + n) * 3;
            float4 ofk = s_off[k];
            inb = exact_inb(lp[0], lp[1], lp[2], ofk.x, ofk.y, ofk.z,
                            s_t[m][0], s_t[m][1], s_t[m][2],
                            s_q[m][0], s_q[m][1], s_q[m][2], s_q[m][3],
                            s_sc[m], s_gcs[m]);
        }
        float gx = fminf(fmaxf(ux - 0.5f, 0.0f), 63.0f);
        float gy = fminf(fmaxf(uy - 0.5f, 0.0f), 63.0f);
        float gz = fminf(fmaxf(uz - 0.5f, 0.0f), 63.0f);
        int ix = min((int)gx, 62);
        int iy = min((int)gy, 62);
        int iz = min((int)gz, 62);
        float fx = gx - (float)ix;
        float fy = gy - (float)iy;
        float fz = gz - (float)iz;
        const float* g = sdf + s_goff[m] + ((ix * GG + iy) * GG + iz);
        float v000 = g[0], v001 = g[1];
        float v010 = g[GG], v011 = g[GG + 1];
        float v100 = g[GG * GG], v101 = g[GG * GG + 1];
        float v110 = g[GG * GG + GG], v111 = g[GG * GG + GG + 1];
        float c00 = v000 + fz * (v001 - v000);
        float c01 = v010 + fz * (v011 - v010);
        float c10 = v100 + fz * (v101 - v100);
        float c11 = v110 + fz * (v111 - v110);
        float c0 = c00 + fy * (c01 - c00);
        float c1 = c10 + fy * (c11 - c10);
        float v = c0 + fx * (c1 - c0);
        v = inb ? v * s_sc[m] : MAXDF;
        dk = fminf(dk, v);
    }
    dd[(size_t)b * N * KK + i] = dk;
}

// --------------- Kernel B: d[27] -> out[32] matvec per point ----------------
__global__ __launch_bounds__(256) void matvec_kernel(
    const float* __restrict__ dd, const float* __restrict__ weight,
    const float* __restrict__ bias, float* __restrict__ out, int N) {
    __shared__ float  s_d[256 * KK];
    __shared__ float4 s_wT4[KK * OUTC / 4];
    __shared__ float  s_bias[OUTC];
    const int b = blockIdx.y;
    const int tid = threadIdx.x;

    float* s_wT = (float*)s_wT4;
    for (int i = tid; i < KK * OUTC; i += 256) {
        int k = i >> 5, o = i & 31;
        s_wT[i] = weight[o * KK + k];
    }
    if (tid < OUTC) s_bias[tid] = bias[tid];

    int p0 = blockIdx.x * 256;
    int cnt = (min(256, N - p0)) * KK;
    const float* src = dd + ((size_t)b * N + p0) * KK;
    int cnt4 = cnt >> 2;
    const float4* s4 = (const float4*)src;
    float4* sd4 = (float4*)s_d;
    for (int i = tid; i < cnt4; i += 256) sd4[i] = s4[i];
    for (int i = cnt4 * 4 + tid; i < cnt; i += 256) s_d[i] = src[i];
    __syncthreads();

    int n = p0 + tid;
    if (n >= N) return;

    float acc[OUTC];
#pragma unroll
    for (int o = 0; o < OUTC; ++o) acc[o] = s_bias[o];

    const float* dl = s_d + tid * KK;
#pragma unroll 1
    for (int k = 0; k < KK; ++k) {
        float dk = dl[k];
#pragma unroll
        for (int j = 0; j < OUTC / 4; ++j) {
            float4 w4 = s_wT4[k * (OUTC / 4) + j];
            acc[4 * j + 0] += dk * w4.x;
            acc[4 * j + 1] += dk * w4.y;
            acc[4 * j + 2] += dk * w4.z;
            acc[4 * j + 3] += dk * w4.w;
        }
    }

    float* op = out + (size_t)(b * N + n) * OUTC;
#pragma unroll
    for (int j = 0; j < OUTC / 4; ++j) {
        float4 v;
        v.x = acc[4 * j + 0]; v.y = acc[4 * j + 1];
        v.z = acc[4 * j + 2]; v.w = acc[4 * j + 3];
        *(float4*)&op[4 * j] = v;
    }
}

extern "C" void kernel_launch(void* const* d_in, const int* in_sizes, int n_in,
                              void* d_out, int out_size, void* d_ws, size_t ws_size,
                              hipStream_t stream) {
    const float* locs   = (const float*)d_in[0];
    const int*   idxs   = (const int*)d_in[1];
    const float* poses  = (const float*)d_in[2];
    const float* scales = (const float*)d_in[3];
    const float* sdf    = (const float*)d_in[4];
    const float* cells  = (const float*)d_in[5];
    const float* weight = (const float*)d_in[6];
    const float* bias   = (const float*)d_in[7];
    float* out = (float*)d_out;

    int B = in_sizes[1] / MM;          // idxs is [B, M]
    int N = in_sizes[0] / (3 * B);     // locs is [B, N, 3]

    float* dd = (float*)d_ws;                          // B*N*27 floats
    float* bu = dd + (size_t)B * N * KK;               // B*N*12 floats

    dim3 gridP((N + 255) / 256, B);
    prep_kernel<<<gridP, 256, 0, stream>>>(locs, idxs, poses, scales, cells, bu, N);

    dim3 gridA((N * KK + 255) / 256, B);
    sample_kernel<<<gridA, 256, 0, stream>>>(locs, idxs, poses, scales, sdf,
                                             cells, bu, dd, N);

    dim3 gridB((N + 255) / 256, B);
    matvec_kernel<<<gridB, 256, 0, stream>>>(dd, weight, bias, out, N);
}

// Round 3
// 28.684 us; speedup vs baseline: 1.3368x; 1.3368x over previous
//
#include <hip/hip_runtime.h>
#include <math.h>

#define KK 27
#define MM 4
#define OUTC 32
#define GG 64
#define DILF 0.05f
#define MAXDF 1.0f
#define MU 4e-3f   // ambiguity margin in grid-units (u-space); FP drift bound ~1e-4

// Bit-exact (numpy op order, no FMA contraction, IEEE div) in-bounds test.
static __device__ inline bool exact_inb(float lx, float ly, float lz,
                                        float ox, float oy, float oz,
                                        float tx, float ty, float tz,
                                        float qx, float qy, float qz, float qw,
                                        float sc, float gcs) {
#pragma clang fp contract(off)
    float px = lx + ox, py = ly + oy, pz = lz + oz;
    float vx = px - tx, vy = py - ty, vz = pz - tz;
    float ux = -qx, uy = -qy, uz = -qz;
    float cx = uy * vz - uz * vy;
    float cy = uz * vx - ux * vz;
    float cz = ux * vy - uy * vx;
    float twx = cx + qw * vx;
    float twy = cy + qw * vy;
    float twz = cz + qw * vz;
    float rx = vx + 2.0f * (uy * twz - uz * twy);
    float ry = vy + 2.0f * (uz * twx - ux * twz);
    float rz = vz + 2.0f * (ux * twy - uy * twx);
    rx = rx / sc; ry = ry / sc; rz = rz / sc;
    return (rx >= 0.0f) & (rx <= gcs) & (ry >= 0.0f) & (ry <= gcs) &
           (rz >= 0.0f) & (rz <= gcs);
}

// One fused kernel. Lane layout: 4 consecutive lanes = 4 models of one point.
// Each lane: rotation for its (point,model), 27-k loop with OOB-predicated
// trilinear gathers, cross-model min via shfl_xor(width 4), 8 outputs/lane.
__global__ __launch_bounds__(256) void convsdf_kernel(
    const float* __restrict__ locs, const int* __restrict__ idxs,
    const float* __restrict__ poses, const float* __restrict__ scales,
    const float* __restrict__ sdf, const float* __restrict__ cells,
    const float* __restrict__ weight, const float* __restrict__ bias,
    float* __restrict__ out, int N) {
    __shared__ float4 s_ro[MM][KK];      // rot_inv(off)/(sc*cs) (u-space)
    __shared__ float4 s_off[KK];         // raw kernel offsets
    __shared__ float4 s_wT4[KK * OUTC / 4];  // wT[k][o]
    __shared__ float  s_bias[OUTC];
    __shared__ float  s_t[MM][3];
    __shared__ float  s_q[MM][4];
    __shared__ float  s_sc[MM];
    __shared__ float  s_gcs[MM];
    __shared__ float  s_invscs[MM];
    __shared__ int    s_goff[MM];

    const int b = blockIdx.y;
    const int tid = threadIdx.x;

    float* s_wT = (float*)s_wT4;
    for (int i = tid; i < KK * OUTC; i += 256) {
        int k = i >> 5, o = i & 31;
        s_wT[i] = weight[o * KK + k];
    }
    if (tid < OUTC) s_bias[tid] = bias[tid];
    if (tid < KK) {
        int kx = tid / 9, ky = (tid / 3) % 3, kz = tid % 3;
        s_off[tid] = make_float4((float)(kx - 1) * DILF, (float)(ky - 1) * DILF,
                                 (float)(kz - 1) * DILF, 0.0f);
    }
    if (tid >= 128 && tid < 128 + MM) {
        int m = tid - 128;
        const float* pp = poses + (b * MM + m) * 7;
        float sc = scales[b * MM + m];
        int gi = idxs[b * MM + m];
        float cs = cells[gi];
        s_t[m][0] = pp[0]; s_t[m][1] = pp[1]; s_t[m][2] = pp[2];
        s_q[m][0] = pp[3]; s_q[m][1] = pp[4]; s_q[m][2] = pp[5]; s_q[m][3] = pp[6];
        s_sc[m] = sc;
        s_gcs[m] = (float)GG * cs;
        s_invscs[m] = 1.0f / (sc * cs);
        s_goff[m] = gi * GG * GG * GG;
    }
    __syncthreads();

    if (tid < MM * KK) {
        int m = tid / KK, k = tid - m * KK;
        float4 off = s_off[k];
        float qx = s_q[m][0], qy = s_q[m][1], qz = s_q[m][2], qw = s_q[m][3];
        float ux = -qx, uy = -qy, uz = -qz;
        float vx = off.x, vy = off.y, vz = off.z;
        float cx = uy * vz - uz * vy + qw * vx;
        float cy = uz * vx - ux * vz + qw * vy;
        float cz = ux * vy - uy * vx + qw * vz;
        float rx = vx + 2.0f * (uy * cz - uz * cy);
        float ry = vy + 2.0f * (uz * cx - ux * cz);
        float rz = vz + 2.0f * (ux * cy - uy * cx);
        float f = s_invscs[m];
        s_ro[m][k] = make_float4(rx * f, ry * f, rz * f, 0.0f);
    }
    __syncthreads();

    const int pl = tid >> 2;          // point-in-block 0..63
    const int m  = tid & 3;           // model 0..3
    const int n  = blockIdx.x * 64 + pl;
    if (n >= N) return;

    const float* lp = locs + (size_t)(b * N + n) * 3;
    float lx = lp[0], ly = lp[1], lz = lp[2];

    // base_u for this (point, model)
    float tx = s_t[m][0], ty = s_t[m][1], tz = s_t[m][2];
    float qx = s_q[m][0], qy = s_q[m][1], qz = s_q[m][2], qw = s_q[m][3];
    float sc = s_sc[m], gcs = s_gcs[m];
    float bux, buy, buz;
    {
        float vx = lx - tx, vy = ly - ty, vz = lz - tz;
        float ux = -qx, uy = -qy, uz = -qz;
        float cx = uy * vz - uz * vy + qw * vx;
        float cy = uz * vx - ux * vz + qw * vy;
        float cz = ux * vy - uy * vx + qw * vz;
        float rx = vx + 2.0f * (uy * cz - uz * cy);
        float ry = vy + 2.0f * (uz * cx - ux * cz);
        float rz = vz + 2.0f * (ux * cy - uy * cx);
        float f = s_invscs[m];
        bux = rx * f; buy = ry * f; buz = rz * f;
    }
    const float* gbase = sdf + s_goff[m];

    float acc[8];
#pragma unroll
    for (int j = 0; j < 8; ++j) acc[j] = s_bias[m * 8 + j];

#pragma unroll 3
    for (int k = 0; k < KK; ++k) {
        float4 ro = s_ro[m][k];
        float ux = bux + ro.x;
        float uy = buy + ro.y;
        float uz = buz + ro.z;
        float mn = fminf(fminf(ux, uy), uz);
        float mx = fmaxf(fmaxf(ux, uy), uz);
        bool inb = (mn >= 0.0f) & (mx <= 64.0f);
        float a0 = fminf(fminf(fabsf(ux), fabsf(uy)), fabsf(uz));
        float a1 = fminf(fminf(fabsf(ux - 64.0f), fabsf(uy - 64.0f)),
                         fabsf(uz - 64.0f));
        if (fminf(a0, a1) < MU) {
            float4 ofk = s_off[k];
            inb = exact_inb(lx, ly, lz, ofk.x, ofk.y, ofk.z,
                            tx, ty, tz, qx, qy, qz, qw, sc, gcs);
        }
        float v = MAXDF;
        if (inb) {   // exec-masked: OOB lanes issue no gather transactions
            float gx = fminf(fmaxf(ux - 0.5f, 0.0f), 63.0f);
            float gy = fminf(fmaxf(uy - 0.5f, 0.0f), 63.0f);
            float gz = fminf(fmaxf(uz - 0.5f, 0.0f), 63.0f);
            int ix = min((int)gx, 62);
            int iy = min((int)gy, 62);
            int iz = min((int)gz, 62);
            float fx = gx - (float)ix;
            float fy = gy - (float)iy;
            float fz = gz - (float)iz;
            const float* g = gbase + ((ix * GG + iy) * GG + iz);
            float v000 = g[0], v001 = g[1];
            float v010 = g[GG], v011 = g[GG + 1];
            float v100 = g[GG * GG], v101 = g[GG * GG + 1];
            float v110 = g[GG * GG + GG], v111 = g[GG * GG + GG + 1];
            float c00 = v000 + fz * (v001 - v000);
            float c01 = v010 + fz * (v011 - v010);
            float c10 = v100 + fz * (v101 - v100);
            float c11 = v110 + fz * (v111 - v110);
            float c0 = c00 + fy * (c01 - c00);
            float c1 = c10 + fy * (c11 - c10);
            v = (c0 + fx * (c1 - c0)) * sc;
        }
        // cross-model min within the 4-lane group
        float dk = v;
        dk = fminf(dk, __shfl_xor(dk, 1, 4));
        dk = fminf(dk, __shfl_xor(dk, 2, 4));
        // accumulate this lane's 8 outputs
        float4 w0 = s_wT4[k * (OUTC / 4) + m * 2 + 0];
        float4 w1 = s_wT4[k * (OUTC / 4) + m * 2 + 1];
        acc[0] += dk * w0.x; acc[1] += dk * w0.y;
        acc[2] += dk * w0.z; acc[3] += dk * w0.w;
        acc[4] += dk * w1.x; acc[5] += dk * w1.y;
        acc[6] += dk * w1.z; acc[7] += dk * w1.w;
    }

    float* op = out + (size_t)(b * N + n) * OUTC + m * 8;
    *(float4*)&op[0] = make_float4(acc[0], acc[1], acc[2], acc[3]);
    *(float4*)&op[4] = make_float4(acc[4], acc[5], acc[6], acc[7]);
}

extern "C" void kernel_launch(void* const* d_in, const int* in_sizes, int n_in,
                              void* d_out, int out_size, void* d_ws, size_t ws_size,
                              hipStream_t stream) {
    const float* locs   = (const float*)d_in[0];
    const int*   idxs   = (const int*)d_in[1];
    const float* poses  = (const float*)d_in[2];
    const float* scales = (const float*)d_in[3];
    const float* sdf    = (const float*)d_in[4];
    const float* cells  = (const float*)d_in[5];
    const float* weight = (const float*)d_in[6];
    const float* bias   = (const float*)d_in[7];
    float* out = (float*)d_out;

    int B = in_sizes[1] / MM;          // idxs is [B, M]
    int N = in_sizes[0] / (3 * B);     // locs is [B, N, 3]

    dim3 grid((N + 63) / 64, B);       // 64 points per 256-thread block
    convsdf_kernel<<<grid, 256, 0, stream>>>(locs, idxs, poses, scales, sdf,
                                             cells, weight, bias, out, N);
}